// Round 9
// baseline (315.135 us; speedup 1.0000x reference)
//
#include <hip/hip_runtime.h>
#include <hip/hip_bf16.h>
#include <math.h>

#define BB 2
#define SS 2048
#define EE 2048
#define HH 16
#define DD 128
#define MM (BB*SS)

typedef __attribute__((ext_vector_type(8))) short bf16x8;
typedef __attribute__((ext_vector_type(4))) float f32x4;
typedef __attribute__((ext_vector_type(16))) float f32x16;
typedef __attribute__((ext_vector_type(4))) unsigned u32x4;

__device__ inline float bf2f(const __hip_bfloat16 h){ return __bfloat162float(h); }
__device__ inline __hip_bfloat16 f2bf(float f){ return __float2bfloat16(f); }
__device__ inline short f2bs(float f){
  union { __hip_bfloat16 h; short s; } u; u.h = __float2bfloat16(f); return u.s;
}
__device__ inline unsigned pk2(float a, float b){
  union { __hip_bfloat162 h2; unsigned u; } x;
  x.h2 = __float22bfloat162_rn(float2{a,b}); return x.u;   // low half = a
}

__device__ inline void gload16(const void* g, void* l){
  __builtin_amdgcn_global_load_lds((const __attribute__((address_space(1))) void*)g,
      (__attribute__((address_space(3))) void*)l, 16, 0, 0);
}

// 1/sqrt(128) * log2(e): folded into Q during RoPE
#define QSCL 0.12754614533018515f

// ---------------- fp32 -> bf16 convert ----------------
__global__ void cvt_kernel(const float* __restrict__ in, __hip_bfloat16* __restrict__ out, int n4){
  int i = blockIdx.x*256 + threadIdx.x;
  if (i >= n4) return;
  float4 v = ((const float4*)in)[i];
  union { short4 s4; short s[4]; } u;
  u.s[0] = f2bs(v.x); u.s[1] = f2bs(v.y); u.s[2] = f2bs(v.z); u.s[3] = f2bs(v.w);
  ((short4*)out)[i] = u.s4;
}

struct P4 { const float* s0; const float* s1; const float* s2; const float* s3;
            __hip_bfloat16* d0; __hip_bfloat16* d1; __hip_bfloat16* d2; __hip_bfloat16* d3; };
__global__ void cvt4_kernel(P4 p, int n4){
  int w = blockIdx.y;
  const float* in = w==0 ? p.s0 : w==1 ? p.s1 : w==2 ? p.s2 : p.s3;
  __hip_bfloat16* out = w==0 ? p.d0 : w==1 ? p.d1 : w==2 ? p.d2 : p.d3;
  int i = blockIdx.x*256 + threadIdx.x;
  if (i >= n4) return;
  float4 v = ((const float4*)in)[i];
  union { short4 s4; short s[4]; } u;
  u.s[0] = f2bs(v.x); u.s[1] = f2bs(v.y); u.s[2] = f2bs(v.z); u.s[3] = f2bs(v.w);
  ((short4*)out)[i] = u.s4;
}

// ---------------- bias concat (bq|bk|bv) ----------------
__global__ void bcat_kernel(const float* __restrict__ bq, const float* __restrict__ bk,
                            const float* __restrict__ bv, float* __restrict__ o){
  int i = blockIdx.x*256 + threadIdx.x;   // 0..6143
  float v = (i < 2048) ? bq[i] : (i < 4096) ? bk[i-2048] : bv[i-4096];
  o[i] = v;
}

// ---------------- RoPE tables ----------------
__global__ void rope_tables_kernel(float* __restrict__ cost, float* __restrict__ sint){
  int idx = blockIdx.x*256 + threadIdx.x;  // SS*64
  int s = idx >> 6, i = idx & 63;
  double inv = exp(-log(10000.0) * (double)i / 64.0);
  double f = (double)s * inv;
  cost[idx] = (float)cos(f);
  sint[idx] = (float)sin(f);
}

// ---------------- RoPE apply on q,k (bf16, in place); q additionally scaled by QSCL ----------------
__global__ void rope_kernel(__hip_bfloat16* __restrict__ q, __hip_bfloat16* __restrict__ k,
                            const float* __restrict__ cost, const float* __restrict__ sint){
  int idx = blockIdx.x*256 + threadIdx.x;   // BB*SS*HH*64
  int i = idx & 63;
  int h = (idx >> 6) & (HH-1);
  int bs = idx >> 10;
  int s = bs & (SS-1);
  float c = cost[s*64 + i], sn = sint[s*64 + i];
  size_t base = ((size_t)bs*HH + h)*DD + i;
  float q1 = bf2f(q[base]), q2 = bf2f(q[base+64]);
  q[base]    = f2bf((q1*c - q2*sn)*QSCL);
  q[base+64] = f2bf((q2*c + q1*sn)*QSCL);
  float k1 = bf2f(k[base]), k2 = bf2f(k[base+64]);
  k[base]    = f2bf(k1*c - k2*sn);
  k[base+64] = f2bf(k2*c + k1*sn);
}

// ---------------- bf16 GEMM, 128x256 tile, BK=64, 8 waves, counted-vmcnt pipeline ----------------
// MODE 0: bf16 C[m*EE+f]; MODE 1: bf16 vt; MODE 2: fp32 C; MODE 3: fused QKV
// (Cout = qb base; kb = +MM*EE, vt = +2*MM*EE elems; tile's section = f>>11).
template<int MODE>
__global__ __launch_bounds__(512) void gemm256(const __hip_bfloat16* __restrict__ A,
        const __hip_bfloat16* __restrict__ Bw, const float* __restrict__ bias,
        void* __restrict__ Cout){
  __shared__ __align__(1024) char lds[98304];
  const int tid = threadIdx.x, wid = tid>>6, lane = tid&63, g = lane>>4, c16 = lane&15;
  const int wm = wid>>2, wn = wid&3;
  const int orig = blockIdx.x;
  const int q8 = (int)gridDim.x >> 3;            // blocks per XCD (grid % 8 == 0)
  const int wg = (orig & 7)*q8 + (orig >> 3);    // bijective XCD swizzle
  const int bm = wg & 31, bn = wg >> 5;
  const int rowA0 = bm*128, rowB0 = bn*256;
  const char* Ab8 = (const char*)A + (size_t)rowA0*4096;
  const char* Bb8 = (const char*)Bw + (size_t)rowB0*4096;

  f32x4 acc[4][4] = {};

  auto stage = [&](int t, int b){
    char* ad = lds + b*49152;
    char* bd = lds + b*49152 + 16384;
    #pragma unroll
    for (int i=0;i<2;i++){
      int off = i*8192 + tid*16;
      int r = off >> 7;
      int cs = (off & 127) ^ ((r&7)<<4);
      gload16(Ab8 + (size_t)r*4096 + t*128 + cs, ad + i*8192 + wid*1024);
    }
    #pragma unroll
    for (int i=0;i<4;i++){
      int off = i*8192 + tid*16;
      int r = off >> 7;
      int cs = (off & 127) ^ ((r&7)<<4);
      gload16(Bb8 + (size_t)r*4096 + t*128 + cs, bd + i*8192 + wid*1024);
    }
  };

  auto compute = [&](int b){
    const char* Abuf = lds + b*49152;
    const char* Bbuf = lds + b*49152 + 16384;
    bf16x8 bfr[4][2];
    #pragma unroll
    for (int ni=0;ni<4;ni++){
      int r = wn*64 + ni*16 + c16;
      int sw = (r&7)<<4;
      #pragma unroll
      for (int kk=0;kk<2;kk++)
        bfr[ni][kk] = *(const bf16x8*)(Bbuf + r*128 + ((kk*64 + g*16) ^ sw));
    }
    #pragma unroll
    for (int mi=0;mi<4;mi++){
      int r = wm*64 + mi*16 + c16;
      int sw = (r&7)<<4;
      bf16x8 af0 = *(const bf16x8*)(Abuf + r*128 + ((g*16) ^ sw));
      bf16x8 af1 = *(const bf16x8*)(Abuf + r*128 + ((64 + g*16) ^ sw));
      __builtin_amdgcn_s_setprio(1);
      #pragma unroll
      for (int ni=0;ni<4;ni++){
        acc[mi][ni] = __builtin_amdgcn_mfma_f32_16x16x32_bf16(af0, bfr[ni][0], acc[mi][ni],0,0,0);
        acc[mi][ni] = __builtin_amdgcn_mfma_f32_16x16x32_bf16(af1, bfr[ni][1], acc[mi][ni],0,0,0);
      }
      __builtin_amdgcn_s_setprio(0);
    }
  };

  stage(0,0);
  stage(1,1);
  asm volatile("s_waitcnt vmcnt(6)" ::: "memory");
  asm volatile("s_barrier" ::: "memory");

  #pragma unroll 1
  for (int tt = 0; tt < 32; tt += 2){
    compute(0);
    asm volatile("s_barrier" ::: "memory");
    if (tt + 2 < 32){ stage(tt+2, 0); asm volatile("s_waitcnt vmcnt(6)" ::: "memory"); }
    else            {                 asm volatile("s_waitcnt vmcnt(0)" ::: "memory"); }
    asm volatile("s_barrier" ::: "memory");
    compute(1);
    if (tt + 2 < 32){
      asm volatile("s_barrier" ::: "memory");
      if (tt + 3 < 32){ stage(tt+3, 1); asm volatile("s_waitcnt vmcnt(6)" ::: "memory"); }
      else            {                 asm volatile("s_waitcnt vmcnt(0)" ::: "memory"); }
      asm volatile("s_barrier" ::: "memory");
    }
  }

  #pragma unroll
  for (int mi=0;mi<4;mi++){
    #pragma unroll
    for (int ni=0;ni<4;ni++){
      int f = rowB0 + wn*64 + ni*16 + c16;
      float bv = bias[f];
      #pragma unroll
      for (int j=0;j<4;j++){
        int m = rowA0 + wm*64 + mi*16 + g*4 + j;
        float v = acc[mi][ni][j] + bv;
        if constexpr (MODE == 0) {
          ((__hip_bfloat16*)Cout)[(size_t)m*EE + f] = f2bf(v);
        } else if constexpr (MODE == 1) {
          int b = m >> 11, s = m & (SS-1);
          ((__hip_bfloat16*)Cout)[((size_t)(b*EE + f))*SS + s] = f2bf(v);
        } else if constexpr (MODE == 2) {
          ((float*)Cout)[(size_t)m*EE + f] = v;
        } else {
          __hip_bfloat16* base = (__hip_bfloat16*)Cout;
          int sec = f >> 11;          // 0=q, 1=k, 2=v (uniform per block)
          int fl  = f & 2047;
          if (sec == 2){
            int b = m >> 11, s = m & (SS-1);
            base[(size_t)2*MM*EE + ((size_t)(b*EE + fl))*SS + s] = f2bf(v);
          } else {
            base[(size_t)sec*MM*EE + (size_t)m*EE + fl] = f2bf(v);
          }
        }
      }
    }
  }
}

// ---------------- flash attention (causal), swapped-QK^T 32x32x16, 4 waves x 32q ----------------
// R4 structure (best measured: 105.8us): 512 blocks, QBLK=128, KVBLK=64,
// K,V double-buffered (64KB), one __syncthreads per iter, independent per-block
// barriers -> phase stagger across the 2 co-resident blocks/CU.
// Q pre-scaled by 1/sqrt(D)*log2e in rope -> softmax uses exp2(p - m) directly.
__global__ __launch_bounds__(256, 2) void attn_kernel(const __hip_bfloat16* __restrict__ qg,
    const __hip_bfloat16* __restrict__ kg, const __hip_bfloat16* __restrict__ vtg,
    __hip_bfloat16* __restrict__ og){
  __shared__ short Ks[2][64*128];   // 16KB x2
  __shared__ short Vs[2][128*64];   // 16KB x2
  const int tid=threadIdx.x, wid=tid>>6, lane=tid&63;
  const int c32 = lane & 31, hi = lane >> 5;
  const int id = blockIdx.x;
  const int u = id & 255;
  const int bh = u & 31, pr = u >> 5;
  const int qtile = (id < 256) ? (15 - pr) : pr;
  const int b = bh >> 4, h = bh & 15;
  const int q0 = qtile*128, qw = q0 + wid*32;
  const int qglob = qw + c32;
  const int niter = 2*qtile + 2;

  const char* kb8 = (const char*)(kg + ((size_t)b*SS)*EE + h*DD);
  const char* vb8 = (const char*)(vtg + (size_t)bh*DD*SS);

  // Q row for this lane: 8 x bf16x8 covering d=0..127
  const char* qrow = (const char*)(qg + ((size_t)(b*SS + qglob))*EE + h*DD);
  bf16x8 qf[8];
  #pragma unroll
  for (int s=0;s<8;s++) qf[s] = *(const bf16x8*)(qrow + s*32 + hi*16);

  f32x16 pacc[4] = {};
  float mrun = -INFINITY, lrun = 0.f;

  auto stageK = [&](int kv, int buf){
    #pragma unroll
    for (int i=0;i<4;i++){
      int base = i*4096 + wid*1024;
      int lb = base + lane*16;
      int r = lb >> 8, cb = lb & 255;
      gload16(kb8 + (size_t)(kv + r)*4096 + (cb ^ ((r&7)<<4)), (char*)Ks[buf] + base);
    }
  };
  auto stageV = [&](int kv, int buf){
    #pragma unroll
    for (int i=0;i<4;i++){
      int base = i*4096 + wid*1024;
      int lb = base + lane*16;
      int d = lb >> 7, cb = lb & 127;
      gload16(vb8 + (size_t)d*4096 + (size_t)kv*2 + (cb ^ ((d&7)<<4)), (char*)Vs[buf] + base);
    }
  };

  stageK(0,0); stageV(0,0);
  __syncthreads();

  int cur = 0;
  #pragma unroll 1
  for (int it = 0; it < niter; ++it){
    const int kv0 = it*64;
    if (it + 1 < niter){ stageK(kv0+64, cur^1); stageV(kv0+64, cur^1); }

    // ---- QK^T: S^T[64kv x 32q], two 32-kv subtiles ----
    f32x16 st0 = {}, st1 = {};
    {
      const char* Kb = (const char*)Ks[cur];
      const int sw = (c32 & 7) << 4;
      __builtin_amdgcn_s_setprio(1);
      #pragma unroll
      for (int s=0;s<8;s++){
        bf16x8 kf0 = *(const bf16x8*)(Kb + c32*256        + ((s*32 + hi*16) ^ sw));
        bf16x8 kf1 = *(const bf16x8*)(Kb + (32+c32)*256   + ((s*32 + hi*16) ^ sw));
        st0 = __builtin_amdgcn_mfma_f32_32x32x16_bf16(kf0, qf[s], st0, 0,0,0);
        st1 = __builtin_amdgcn_mfma_f32_32x32x16_bf16(kf1, qf[s], st1, 0,0,0);
      }
      __builtin_amdgcn_s_setprio(0);
    }

    // ---- mask + in-register online softmax (q = lane column; S pre-scaled) ----
    float p[32];
    float vmax = -INFINITY;
    const bool domask = (kv0 + 63 > qw);
    #pragma unroll
    for (int r=0;r<16;r++){
      float v0 = st0[r], v1 = st1[r];
      if (domask){
        int kvo = (r&3) + 8*(r>>2) + 4*hi;
        if (kv0 + kvo > qglob)      v0 = -INFINITY;
        if (kv0 + 32 + kvo > qglob) v1 = -INFINITY;
      }
      p[r] = v0; p[16+r] = v1;
      vmax = fmaxf(vmax, fmaxf(v0, v1));
    }
    vmax = fmaxf(vmax, __shfl_xor(vmax, 32));

    const bool anynew = !__all(vmax <= mrun);
    float mnew = mrun;
    if (anynew){
      mnew = fmaxf(mrun, vmax);
      const float rs = exp2f(mrun - mnew);
      mrun = mnew;
      lrun *= rs;
      #pragma unroll
      for (int ds=0; ds<4; ds++)
        #pragma unroll
        for (int r=0;r<16;r++) pacc[ds][r] *= rs;
    }

    float s0=0.f, s1=0.f, s2=0.f, s3=0.f;
    #pragma unroll
    for (int i=0;i<8;i++){
      p[i]    = exp2f(p[i]    - mnew); s0 += p[i];
      p[8+i]  = exp2f(p[8+i]  - mnew); s1 += p[8+i];
      p[16+i] = exp2f(p[16+i] - mnew); s2 += p[16+i];
      p[24+i] = exp2f(p[24+i] - mnew); s3 += p[24+i];
    }
    float ps = (s0 + s1) + (s2 + s3);
    ps += __shfl_xor(ps, 32);
    lrun += ps;

    // ---- pack P to bf16 words: w[T][m][u] holds kv = 32T + 8m + 4hi + 2u ----
    unsigned w[2][4][2];
    #pragma unroll
    for (int T=0;T<2;T++)
      #pragma unroll
      for (int m=0;m<4;m++)
        #pragma unroll
        for (int uu=0;uu<2;uu++)
          w[T][m][uu] = pk2(p[T*16 + 4*m + 2*uu], p[T*16 + 4*m + 2*uu + 1]);

    // ---- build PV B-fragments: pf[ks] covers kv = 16ks + 8hi + 0..7 ----
    bf16x8 pf[4];
    #pragma unroll
    for (int ks=0; ks<4; ks++){
      int T = ks>>1, lo2 = (ks&1)*2;
      unsigned o0 = hi ? w[T][lo2+1][0] : w[T][lo2+0][0];
      unsigned o1 = hi ? w[T][lo2+1][1] : w[T][lo2+0][1];
      unsigned x0 = hi ? w[T][lo2+0][0] : w[T][lo2+1][0];
      unsigned x1 = hi ? w[T][lo2+0][1] : w[T][lo2+1][1];
      unsigned r0 = (unsigned)__shfl_xor((int)x0, 32);
      unsigned r1 = (unsigned)__shfl_xor((int)x1, 32);
      union { u32x4 u4; bf16x8 h8; } cvt;
      cvt.u4[0] = hi ? r0 : o0;
      cvt.u4[1] = hi ? r1 : o1;
      cvt.u4[2] = hi ? o0 : r0;
      cvt.u4[3] = hi ? o1 : r1;
      pf[ks] = cvt.h8;
    }

    // ---- PV: O^T[d][q] += Vt * P ----
    {
      const char* Vb = (const char*)Vs[cur];
      const int vsw = (c32 & 7) << 4;
      __builtin_amdgcn_s_setprio(1);
      #pragma unroll
      for (int ds=0; ds<4; ds++){
        const char* vr = Vb + (ds*32 + c32)*128;
        #pragma unroll
        for (int ks=0; ks<4; ks++){
          bf16x8 vf = *(const bf16x8*)(vr + ((ks*32 + hi*16) ^ vsw));
          pacc[ds] = __builtin_amdgcn_mfma_f32_32x32x16_bf16(vf, pf[ks], pacc[ds], 0,0,0);
        }
      }
      __builtin_amdgcn_s_setprio(0);
    }

    __syncthreads();
    cur ^= 1;
  }

  // ---- epilogue: O[q][d] = pacc^T / lrun ----
  const float invl = 1.0f / lrun;
  char* orow = (char*)(og + ((size_t)(b*SS + qglob))*EE + h*DD);
  #pragma unroll
  for (int ds=0; ds<4; ds++){
    #pragma unroll
    for (int m=0;m<4;m++){
      int d0 = ds*32 + 8*m + 4*hi;
      short4 s4;
      s4.x = f2bs(pacc[ds][4*m+0]*invl);
      s4.y = f2bs(pacc[ds][4*m+1]*invl);
      s4.z = f2bs(pacc[ds][4*m+2]*invl);
      s4.w = f2bs(pacc[ds][4*m+3]*invl);
      *(short4*)(orow + d0*2) = s4;
    }
  }
}

extern "C" void kernel_launch(void* const* d_in, const int* in_sizes, int n_in,
                              void* d_out, int out_size, void* d_ws, size_t ws_size,
                              hipStream_t stream){
  const float* x  = (const float*)d_in[0];
  const float* Wq = (const float*)d_in[1];
  const float* bq = (const float*)d_in[2];
  const float* Wk = (const float*)d_in[3];
  const float* bk = (const float*)d_in[4];
  const float* Wv = (const float*)d_in[5];
  const float* bv = (const float*)d_in[6];
  const float* Wp = (const float*)d_in[7];
  const float* bp = (const float*)d_in[8];
  float* out = (float*)d_out;

  char* ws = (char*)d_ws;
  size_t off = 0;
  auto alloc = [&](size_t bytes){ void* p = ws + off; off += (bytes + 255) & ~(size_t)255; return p; };
  const size_t nx = (size_t)MM*EE;
  const size_t nw = (size_t)EE*EE;
  // NOTE: wqb/wkb/wvb contiguous (fused [6144][2048] weight); qb/kb/vtb contiguous.
  __hip_bfloat16* xb  = (__hip_bfloat16*)alloc(nx*2);
  __hip_bfloat16* wqb = (__hip_bfloat16*)alloc(nw*2);
  __hip_bfloat16* wkb = (__hip_bfloat16*)alloc(nw*2);
  __hip_bfloat16* wvb = (__hip_bfloat16*)alloc(nw*2);
  __hip_bfloat16* wpb = (__hip_bfloat16*)alloc(nw*2);
  __hip_bfloat16* qb  = (__hip_bfloat16*)alloc(nx*2);
  __hip_bfloat16* kb  = (__hip_bfloat16*)alloc(nx*2);
  __hip_bfloat16* vtb = (__hip_bfloat16*)alloc(nx*2);
  __hip_bfloat16* ob  = (__hip_bfloat16*)alloc(nx*2);
  float* cost = (float*)alloc((size_t)SS*64*4);
  float* sint = (float*)alloc((size_t)SS*64*4);
  float* bqkv = (float*)alloc((size_t)3*EE*4);

  cvt_kernel<<<(int)(nx/4/256), 256, 0, stream>>>(x, xb, (int)(nx/4));
  P4 p4{Wq, Wk, Wv, Wp, wqb, wkb, wvb, wpb};
  cvt4_kernel<<<dim3((int)(nw/4/256), 4), 256, 0, stream>>>(p4, (int)(nw/4));
  bcat_kernel<<<24, 256, 0, stream>>>(bq, bk, bv, bqkv);
  rope_tables_kernel<<<SS*64/256, 256, 0, stream>>>(cost, sint);

  // fused QKV GEMM: A = xb [4096][2048], W = wqb base [6144][2048], out -> qb/kb/vtb
  gemm256<3><<<768, 512, 0, stream>>>(xb, wqb, bqkv, qb);

  rope_kernel<<<(BB*SS*HH*64)/256, 256, 0, stream>>>(qb, kb, cost, sint);

  attn_kernel<<<dim3(512), 256, 0, stream>>>(qb, kb, vtb, ob);

  gemm256<2><<<256, 512, 0, stream>>>(ob, wpb, bp, out);
}

// Round 11
// 288.092 us; speedup vs baseline: 1.0939x; 1.0939x over previous
//
#include <hip/hip_runtime.h>
#include <hip/hip_bf16.h>
#include <math.h>

#define BB 2
#define SS 2048
#define EE 2048
#define HH 16
#define DD 128
#define MM (BB*SS)

typedef __attribute__((ext_vector_type(8))) short bf16x8;
typedef __attribute__((ext_vector_type(4))) float f32x4;
typedef __attribute__((ext_vector_type(16))) float f32x16;
typedef __attribute__((ext_vector_type(4))) unsigned u32x4;

__device__ inline float bf2f(const __hip_bfloat16 h){ return __bfloat162float(h); }
__device__ inline __hip_bfloat16 f2bf(float f){ return __float2bfloat16(f); }
__device__ inline short f2bs(float f){
  union { __hip_bfloat16 h; short s; } u; u.h = __float2bfloat16(f); return u.s;
}
__device__ inline unsigned pk2(float a, float b){
  union { __hip_bfloat162 h2; unsigned u; } x;
  x.h2 = __float22bfloat162_rn(float2{a,b}); return x.u;   // low half = a
}

__device__ inline void gload16(const void* g, void* l){
  __builtin_amdgcn_global_load_lds((const __attribute__((address_space(1))) void*)g,
      (__attribute__((address_space(3))) void*)l, 16, 0, 0);
}

// 1/sqrt(128) * log2(e): folded into Q during RoPE
#define QSCL 0.12754614533018515f

// ---------------- fp32 -> bf16 convert ----------------
__global__ void cvt_kernel(const float* __restrict__ in, __hip_bfloat16* __restrict__ out, int n4){
  int i = blockIdx.x*256 + threadIdx.x;
  if (i >= n4) return;
  float4 v = ((const float4*)in)[i];
  union { short4 s4; short s[4]; } u;
  u.s[0] = f2bs(v.x); u.s[1] = f2bs(v.y); u.s[2] = f2bs(v.z); u.s[3] = f2bs(v.w);
  ((short4*)out)[i] = u.s4;
}

struct P4 { const float* s0; const float* s1; const float* s2; const float* s3;
            __hip_bfloat16* d0; __hip_bfloat16* d1; __hip_bfloat16* d2; __hip_bfloat16* d3; };
__global__ void cvt4_kernel(P4 p, int n4){
  int w = blockIdx.y;
  const float* in = w==0 ? p.s0 : w==1 ? p.s1 : w==2 ? p.s2 : p.s3;
  __hip_bfloat16* out = w==0 ? p.d0 : w==1 ? p.d1 : w==2 ? p.d2 : p.d3;
  int i = blockIdx.x*256 + threadIdx.x;
  if (i >= n4) return;
  float4 v = ((const float4*)in)[i];
  union { short4 s4; short s[4]; } u;
  u.s[0] = f2bs(v.x); u.s[1] = f2bs(v.y); u.s[2] = f2bs(v.z); u.s[3] = f2bs(v.w);
  ((short4*)out)[i] = u.s4;
}

// ---------------- RoPE tables ----------------
__global__ void rope_tables_kernel(float* __restrict__ cost, float* __restrict__ sint){
  int idx = blockIdx.x*256 + threadIdx.x;  // SS*64
  int s = idx >> 6, i = idx & 63;
  double inv = exp(-log(10000.0) * (double)i / 64.0);
  double f = (double)s * inv;
  cost[idx] = (float)cos(f);
  sint[idx] = (float)sin(f);
}

// ---------------- RoPE apply on q,k (bf16, in place); q additionally scaled by QSCL ----------------
__global__ void rope_kernel(__hip_bfloat16* __restrict__ q, __hip_bfloat16* __restrict__ k,
                            const float* __restrict__ cost, const float* __restrict__ sint){
  int idx = blockIdx.x*256 + threadIdx.x;   // BB*SS*HH*64
  int i = idx & 63;
  int h = (idx >> 6) & (HH-1);
  int bs = idx >> 10;
  int s = bs & (SS-1);
  float c = cost[s*64 + i], sn = sint[s*64 + i];
  size_t base = ((size_t)bs*HH + h)*DD + i;
  float q1 = bf2f(q[base]), q2 = bf2f(q[base+64]);
  q[base]    = f2bf((q1*c - q2*sn)*QSCL);
  q[base+64] = f2bf((q2*c + q1*sn)*QSCL);
  float k1 = bf2f(k[base]), k2 = bf2f(k[base+64]);
  k[base]    = f2bf(k1*c - k2*sn);
  k[base+64] = f2bf(k2*c + k1*sn);
}

// ---------------- bf16 GEMM, 128x256 tile, BK=64, 8 waves, counted-vmcnt pipeline ----------------
// MODE 0: bf16 C[m*EE+f]; MODE 1: bf16 vt[(b*EE+f)*SS+s]; MODE 2: fp32 C
template<int MODE>
__global__ __launch_bounds__(512) void gemm256(const __hip_bfloat16* __restrict__ A,
        const __hip_bfloat16* __restrict__ Bw, const float* __restrict__ bias,
        void* __restrict__ Cout){
  __shared__ __align__(1024) char lds[98304];
  const int tid = threadIdx.x, wid = tid>>6, lane = tid&63, g = lane>>4, c16 = lane&15;
  const int wm = wid>>2, wn = wid&3;
  const int orig = blockIdx.x;
  const int wg = (orig & 7)*32 + (orig >> 3);   // bijective XCD swizzle (grid 256)
  const int bm = wg & 31, bn = wg >> 5;
  const int rowA0 = bm*128, rowB0 = bn*256;
  const char* Ab8 = (const char*)A + (size_t)rowA0*4096;
  const char* Bb8 = (const char*)Bw + (size_t)rowB0*4096;

  f32x4 acc[4][4] = {};

  auto stage = [&](int t, int b){
    char* ad = lds + b*49152;
    char* bd = lds + b*49152 + 16384;
    #pragma unroll
    for (int i=0;i<2;i++){
      int off = i*8192 + tid*16;
      int r = off >> 7;
      int cs = (off & 127) ^ ((r&7)<<4);
      gload16(Ab8 + (size_t)r*4096 + t*128 + cs, ad + i*8192 + wid*1024);
    }
    #pragma unroll
    for (int i=0;i<4;i++){
      int off = i*8192 + tid*16;
      int r = off >> 7;
      int cs = (off & 127) ^ ((r&7)<<4);
      gload16(Bb8 + (size_t)r*4096 + t*128 + cs, bd + i*8192 + wid*1024);
    }
  };

  auto compute = [&](int b){
    const char* Abuf = lds + b*49152;
    const char* Bbuf = lds + b*49152 + 16384;
    bf16x8 bfr[4][2];
    #pragma unroll
    for (int ni=0;ni<4;ni++){
      int r = wn*64 + ni*16 + c16;
      int sw = (r&7)<<4;
      #pragma unroll
      for (int kk=0;kk<2;kk++)
        bfr[ni][kk] = *(const bf16x8*)(Bbuf + r*128 + ((kk*64 + g*16) ^ sw));
    }
    #pragma unroll
    for (int mi=0;mi<4;mi++){
      int r = wm*64 + mi*16 + c16;
      int sw = (r&7)<<4;
      bf16x8 af0 = *(const bf16x8*)(Abuf + r*128 + ((g*16) ^ sw));
      bf16x8 af1 = *(const bf16x8*)(Abuf + r*128 + ((64 + g*16) ^ sw));
      __builtin_amdgcn_s_setprio(1);
      #pragma unroll
      for (int ni=0;ni<4;ni++){
        acc[mi][ni] = __builtin_amdgcn_mfma_f32_16x16x32_bf16(af0, bfr[ni][0], acc[mi][ni],0,0,0);
        acc[mi][ni] = __builtin_amdgcn_mfma_f32_16x16x32_bf16(af1, bfr[ni][1], acc[mi][ni],0,0,0);
      }
      __builtin_amdgcn_s_setprio(0);
    }
  };

  stage(0,0);
  stage(1,1);
  asm volatile("s_waitcnt vmcnt(6)" ::: "memory");
  asm volatile("s_barrier" ::: "memory");

  #pragma unroll 1
  for (int tt = 0; tt < 32; tt += 2){
    compute(0);
    asm volatile("s_barrier" ::: "memory");
    if (tt + 2 < 32){ stage(tt+2, 0); asm volatile("s_waitcnt vmcnt(6)" ::: "memory"); }
    else            {                 asm volatile("s_waitcnt vmcnt(0)" ::: "memory"); }
    asm volatile("s_barrier" ::: "memory");
    compute(1);
    if (tt + 2 < 32){
      asm volatile("s_barrier" ::: "memory");
      if (tt + 3 < 32){ stage(tt+3, 1); asm volatile("s_waitcnt vmcnt(6)" ::: "memory"); }
      else            {                 asm volatile("s_waitcnt vmcnt(0)" ::: "memory"); }
      asm volatile("s_barrier" ::: "memory");
    }
  }

  #pragma unroll
  for (int mi=0;mi<4;mi++){
    #pragma unroll
    for (int ni=0;ni<4;ni++){
      int f = rowB0 + wn*64 + ni*16 + c16;
      float bv = bias[f];
      #pragma unroll
      for (int j=0;j<4;j++){
        int m = rowA0 + wm*64 + mi*16 + g*4 + j;
        float v = acc[mi][ni][j] + bv;
        if constexpr (MODE == 0) {
          ((__hip_bfloat16*)Cout)[(size_t)m*EE + f] = f2bf(v);
        } else if constexpr (MODE == 1) {
          int b = m >> 11, s = m & (SS-1);
          ((__hip_bfloat16*)Cout)[((size_t)(b*EE + f))*SS + s] = f2bf(v);
        } else {
          ((float*)Cout)[(size_t)m*EE + f] = v;
        }
      }
    }
  }
}

// ---------------- flash attention (causal), swapped-QK^T 32x32x16, 4 waves x 32q ----------------
// R4 structure (best measured): 512 blocks, QBLK=128, KVBLK=64, K,V double-buffered
// (64KB), one __syncthreads per iter, independent per-block barriers -> phase
// stagger across the 2 co-resident blocks/CU. Q pre-scaled by 1/sqrt(D)*log2e.
__global__ __launch_bounds__(256, 2) void attn_kernel(const __hip_bfloat16* __restrict__ qg,
    const __hip_bfloat16* __restrict__ kg, const __hip_bfloat16* __restrict__ vtg,
    __hip_bfloat16* __restrict__ og){
  __shared__ short Ks[2][64*128];   // 16KB x2
  __shared__ short Vs[2][128*64];   // 16KB x2
  const int tid=threadIdx.x, wid=tid>>6, lane=tid&63;
  const int c32 = lane & 31, hi = lane >> 5;
  const int id = blockIdx.x;
  const int u = id & 255;
  const int bh = u & 31, pr = u >> 5;
  const int qtile = (id < 256) ? (15 - pr) : pr;
  const int b = bh >> 4, h = bh & 15;
  const int q0 = qtile*128, qw = q0 + wid*32;
  const int qglob = qw + c32;
  const int niter = 2*qtile + 2;

  const char* kb8 = (const char*)(kg + ((size_t)b*SS)*EE + h*DD);
  const char* vb8 = (const char*)(vtg + (size_t)bh*DD*SS);

  // Q row for this lane: 8 x bf16x8 covering d=0..127
  const char* qrow = (const char*)(qg + ((size_t)(b*SS + qglob))*EE + h*DD);
  bf16x8 qf[8];
  #pragma unroll
  for (int s=0;s<8;s++) qf[s] = *(const bf16x8*)(qrow + s*32 + hi*16);

  f32x16 pacc[4] = {};
  float mrun = -INFINITY, lrun = 0.f;

  auto stageK = [&](int kv, int buf){
    #pragma unroll
    for (int i=0;i<4;i++){
      int base = i*4096 + wid*1024;
      int lb = base + lane*16;
      int r = lb >> 8, cb = lb & 255;
      gload16(kb8 + (size_t)(kv + r)*4096 + (cb ^ ((r&7)<<4)), (char*)Ks[buf] + base);
    }
  };
  auto stageV = [&](int kv, int buf){
    #pragma unroll
    for (int i=0;i<4;i++){
      int base = i*4096 + wid*1024;
      int lb = base + lane*16;
      int d = lb >> 7, cb = lb & 127;
      gload16(vb8 + (size_t)d*4096 + (size_t)kv*2 + (cb ^ ((d&7)<<4)), (char*)Vs[buf] + base);
    }
  };

  stageK(0,0); stageV(0,0);
  __syncthreads();

  int cur = 0;
  #pragma unroll 1
  for (int it = 0; it < niter; ++it){
    const int kv0 = it*64;
    if (it + 1 < niter){ stageK(kv0+64, cur^1); stageV(kv0+64, cur^1); }

    // ---- QK^T: S^T[64kv x 32q], two 32-kv subtiles ----
    f32x16 st0 = {}, st1 = {};
    {
      const char* Kb = (const char*)Ks[cur];
      const int sw = (c32 & 7) << 4;
      __builtin_amdgcn_s_setprio(1);
      #pragma unroll
      for (int s=0;s<8;s++){
        bf16x8 kf0 = *(const bf16x8*)(Kb + c32*256        + ((s*32 + hi*16) ^ sw));
        bf16x8 kf1 = *(const bf16x8*)(Kb + (32+c32)*256   + ((s*32 + hi*16) ^ sw));
        st0 = __builtin_amdgcn_mfma_f32_32x32x16_bf16(kf0, qf[s], st0, 0,0,0);
        st1 = __builtin_amdgcn_mfma_f32_32x32x16_bf16(kf1, qf[s], st1, 0,0,0);
      }
      __builtin_amdgcn_s_setprio(0);
    }

    // ---- mask + in-register online softmax (q = lane column; S pre-scaled) ----
    float p[32];
    float vmax = -INFINITY;
    const bool domask = (kv0 + 63 > qw);
    #pragma unroll
    for (int r=0;r<16;r++){
      float v0 = st0[r], v1 = st1[r];
      if (domask){
        int kvo = (r&3) + 8*(r>>2) + 4*hi;
        if (kv0 + kvo > qglob)      v0 = -INFINITY;
        if (kv0 + 32 + kvo > qglob) v1 = -INFINITY;
      }
      p[r] = v0; p[16+r] = v1;
      vmax = fmaxf(vmax, fmaxf(v0, v1));
    }
    vmax = fmaxf(vmax, __shfl_xor(vmax, 32));

    const bool anynew = !__all(vmax <= mrun);
    float mnew = mrun;
    if (anynew){
      mnew = fmaxf(mrun, vmax);
      const float rs = exp2f(mrun - mnew);
      mrun = mnew;
      lrun *= rs;
      #pragma unroll
      for (int ds=0; ds<4; ds++)
        #pragma unroll
        for (int r=0;r<16;r++) pacc[ds][r] *= rs;
    }

    float s0=0.f, s1=0.f, s2=0.f, s3=0.f;
    #pragma unroll
    for (int i=0;i<8;i++){
      p[i]    = exp2f(p[i]    - mnew); s0 += p[i];
      p[8+i]  = exp2f(p[8+i]  - mnew); s1 += p[8+i];
      p[16+i] = exp2f(p[16+i] - mnew); s2 += p[16+i];
      p[24+i] = exp2f(p[24+i] - mnew); s3 += p[24+i];
    }
    float ps = (s0 + s1) + (s2 + s3);
    ps += __shfl_xor(ps, 32);
    lrun += ps;

    // ---- pack P to bf16 words: w[T][m][u] holds kv = 32T + 8m + 4hi + 2u ----
    unsigned w[2][4][2];
    #pragma unroll
    for (int T=0;T<2;T++)
      #pragma unroll
      for (int m=0;m<4;m++)
        #pragma unroll
        for (int uu=0;uu<2;uu++)
          w[T][m][uu] = pk2(p[T*16 + 4*m + 2*uu], p[T*16 + 4*m + 2*uu + 1]);

    // ---- build PV B-fragments: pf[ks] covers kv = 16ks + 8hi + 0..7 ----
    bf16x8 pf[4];
    #pragma unroll
    for (int ks=0; ks<4; ks++){
      int T = ks>>1, lo2 = (ks&1)*2;
      unsigned o0 = hi ? w[T][lo2+1][0] : w[T][lo2+0][0];
      unsigned o1 = hi ? w[T][lo2+1][1] : w[T][lo2+0][1];
      unsigned x0 = hi ? w[T][lo2+0][0] : w[T][lo2+1][0];
      unsigned x1 = hi ? w[T][lo2+0][1] : w[T][lo2+1][1];
      unsigned r0 = (unsigned)__shfl_xor((int)x0, 32);
      unsigned r1 = (unsigned)__shfl_xor((int)x1, 32);
      union { u32x4 u4; bf16x8 h8; } cvt;
      cvt.u4[0] = hi ? r0 : o0;
      cvt.u4[1] = hi ? r1 : o1;
      cvt.u4[2] = hi ? o0 : r0;
      cvt.u4[3] = hi ? o1 : r1;
      pf[ks] = cvt.h8;
    }

    // ---- PV: O^T[d][q] += Vt * P ----
    {
      const char* Vb = (const char*)Vs[cur];
      const int vsw = (c32 & 7) << 4;
      __builtin_amdgcn_s_setprio(1);
      #pragma unroll
      for (int ds=0; ds<4; ds++){
        const char* vr = Vb + (ds*32 + c32)*128;
        #pragma unroll
        for (int ks=0; ks<4; ks++){
          bf16x8 vf = *(const bf16x8*)(vr + ((ks*32 + hi*16) ^ vsw));
          pacc[ds] = __builtin_amdgcn_mfma_f32_32x32x16_bf16(vf, pf[ks], pacc[ds], 0,0,0);
        }
      }
      __builtin_amdgcn_s_setprio(0);
    }

    __syncthreads();
    cur ^= 1;
  }

  // ---- epilogue: O[q][d] = pacc^T / lrun ----
  const float invl = 1.0f / lrun;
  char* orow = (char*)(og + ((size_t)(b*SS + qglob))*EE + h*DD);
  #pragma unroll
  for (int ds=0; ds<4; ds++){
    #pragma unroll
    for (int m=0;m<4;m++){
      int d0 = ds*32 + 8*m + 4*hi;
      short4 s4;
      s4.x = f2bs(pacc[ds][4*m+0]*invl);
      s4.y = f2bs(pacc[ds][4*m+1]*invl);
      s4.z = f2bs(pacc[ds][4*m+2]*invl);
      s4.w = f2bs(pacc[ds][4*m+3]*invl);
      *(short4*)(orow + d0*2) = s4;
    }
  }
}

extern "C" void kernel_launch(void* const* d_in, const int* in_sizes, int n_in,
                              void* d_out, int out_size, void* d_ws, size_t ws_size,
                              hipStream_t stream){
  const float* x  = (const float*)d_in[0];
  const float* Wq = (const float*)d_in[1];
  const float* bq = (const float*)d_in[2];
  const float* Wk = (const float*)d_in[3];
  const float* bk = (const float*)d_in[4];
  const float* Wv = (const float*)d_in[5];
  const float* bv = (const float*)d_in[6];
  const float* Wp = (const float*)d_in[7];
  const float* bp = (const float*)d_in[8];
  float* out = (float*)d_out;

  char* ws = (char*)d_ws;
  size_t off = 0;
  auto alloc = [&](size_t bytes){ void* p = ws + off; off += (bytes + 255) & ~(size_t)255; return p; };
  const size_t nx = (size_t)MM*EE;
  const size_t nw = (size_t)EE*EE;
  __hip_bfloat16* xb  = (__hip_bfloat16*)alloc(nx*2);
  __hip_bfloat16* wqb = (__hip_bfloat16*)alloc(nw*2);
  __hip_bfloat16* wkb = (__hip_bfloat16*)alloc(nw*2);
  __hip_bfloat16* wvb = (__hip_bfloat16*)alloc(nw*2);
  __hip_bfloat16* wpb = (__hip_bfloat16*)alloc(nw*2);
  __hip_bfloat16* qb  = (__hip_bfloat16*)alloc(nx*2);
  __hip_bfloat16* kb  = (__hip_bfloat16*)alloc(nx*2);
  __hip_bfloat16* vtb = (__hip_bfloat16*)alloc(nx*2);
  __hip_bfloat16* ob  = (__hip_bfloat16*)alloc(nx*2);
  float* cost = (float*)alloc((size_t)SS*64*4);
  float* sint = (float*)alloc((size_t)SS*64*4);

  cvt_kernel<<<(int)(nx/4/256), 256, 0, stream>>>(x, xb, (int)(nx/4));
  P4 p4{Wq, Wk, Wv, Wp, wqb, wkb, wvb, wpb};
  cvt4_kernel<<<dim3((int)(nw/4/256), 4), 256, 0, stream>>>(p4, (int)(nw/4));
  rope_tables_kernel<<<SS*64/256, 256, 0, stream>>>(cost, sint);

  gemm256<0><<<256, 512, 0, stream>>>(xb, wqb, bq, qb);
  gemm256<0><<<256, 512, 0, stream>>>(xb, wkb, bk, kb);
  gemm256<1><<<256, 512, 0, stream>>>(xb, wvb, bv, vtb);

  rope_kernel<<<(BB*SS*HH*64)/256, 256, 0, stream>>>(qb, kb, cost, sint);

  attn_kernel<<<dim3(512), 256, 0, stream>>>(qb, kb, vtb, ob);

  gemm256<2><<<256, 512, 0, stream>>>(ob, wpb, bp, out);
}

// Round 12
// 275.404 us; speedup vs baseline: 1.1443x; 1.0461x over previous
//
#include <hip/hip_runtime.h>
#include <hip/hip_bf16.h>
#include <math.h>

#define BB 2
#define SS 2048
#define EE 2048
#define HH 16
#define DD 128
#define MM (BB*SS)

typedef __attribute__((ext_vector_type(8))) short bf16x8;
typedef __attribute__((ext_vector_type(4))) float f32x4;
typedef __attribute__((ext_vector_type(16))) float f32x16;
typedef __attribute__((ext_vector_type(4))) unsigned u32x4;

__device__ inline float bf2f(const __hip_bfloat16 h){ return __bfloat162float(h); }
__device__ inline __hip_bfloat16 f2bf(float f){ return __float2bfloat16(f); }
__device__ inline short f2bs(float f){
  union { __hip_bfloat16 h; short s; } u; u.h = __float2bfloat16(f); return u.s;
}
__device__ inline unsigned pk2(float a, float b){
  union { __hip_bfloat162 h2; unsigned u; } x;
  x.h2 = __float22bfloat162_rn(float2{a,b}); return x.u;   // low half = a
}

__device__ inline void gload16(const void* g, void* l){
  __builtin_amdgcn_global_load_lds((const __attribute__((address_space(1))) void*)g,
      (__attribute__((address_space(3))) void*)l, 16, 0, 0);
}

// 1/sqrt(128) * log2(e): folded into Q during RoPE
#define QSCL 0.12754614533018515f

// ---------------- fp32 -> bf16 convert ----------------
__global__ void cvt_kernel(const float* __restrict__ in, __hip_bfloat16* __restrict__ out, int n4){
  int i = blockIdx.x*256 + threadIdx.x;
  if (i >= n4) return;
  float4 v = ((const float4*)in)[i];
  union { short4 s4; short s[4]; } u;
  u.s[0] = f2bs(v.x); u.s[1] = f2bs(v.y); u.s[2] = f2bs(v.z); u.s[3] = f2bs(v.w);
  ((short4*)out)[i] = u.s4;
}

struct P4 { const float* s0; const float* s1; const float* s2; const float* s3;
            __hip_bfloat16* d0; __hip_bfloat16* d1; __hip_bfloat16* d2; __hip_bfloat16* d3; };
__global__ void cvt4_kernel(P4 p, int n4){
  int w = blockIdx.y;
  const float* in = w==0 ? p.s0 : w==1 ? p.s1 : w==2 ? p.s2 : p.s3;
  __hip_bfloat16* out = w==0 ? p.d0 : w==1 ? p.d1 : w==2 ? p.d2 : p.d3;
  int i = blockIdx.x*256 + threadIdx.x;
  if (i >= n4) return;
  float4 v = ((const float4*)in)[i];
  union { short4 s4; short s[4]; } u;
  u.s[0] = f2bs(v.x); u.s[1] = f2bs(v.y); u.s[2] = f2bs(v.z); u.s[3] = f2bs(v.w);
  ((short4*)out)[i] = u.s4;
}

// ---------------- RoPE tables ----------------
__global__ void rope_tables_kernel(float* __restrict__ cost, float* __restrict__ sint){
  int idx = blockIdx.x*256 + threadIdx.x;  // SS*64
  int s = idx >> 6, i = idx & 63;
  double inv = exp(-log(10000.0) * (double)i / 64.0);
  double f = (double)s * inv;
  cost[idx] = (float)cos(f);
  sint[idx] = (float)sin(f);
}

// ---------------- RoPE apply on q,k (bf16, in place); q additionally scaled by QSCL ----------------
__global__ void rope_kernel(__hip_bfloat16* __restrict__ q, __hip_bfloat16* __restrict__ k,
                            const float* __restrict__ cost, const float* __restrict__ sint){
  int idx = blockIdx.x*256 + threadIdx.x;   // BB*SS*HH*64
  int i = idx & 63;
  int h = (idx >> 6) & (HH-1);
  int bs = idx >> 10;
  int s = bs & (SS-1);
  float c = cost[s*64 + i], sn = sint[s*64 + i];
  size_t base = ((size_t)bs*HH + h)*DD + i;
  float q1 = bf2f(q[base]), q2 = bf2f(q[base+64]);
  q[base]    = f2bf((q1*c - q2*sn)*QSCL);
  q[base+64] = f2bf((q2*c + q1*sn)*QSCL);
  float k1 = bf2f(k[base]), k2 = bf2f(k[base+64]);
  k[base]    = f2bf(k1*c - k2*sn);
  k[base+64] = f2bf(k2*c + k1*sn);
}

// ---------------- bf16 GEMM, 128x256 tile, BK=64, 8 waves, counted-vmcnt pipeline ----------------
// MODE 0: bf16 C[m*EE+f]; MODE 1: bf16 vt[(b*EE+f)*SS+s]; MODE 2: fp32 C
template<int MODE>
__global__ __launch_bounds__(512) void gemm256(const __hip_bfloat16* __restrict__ A,
        const __hip_bfloat16* __restrict__ Bw, const float* __restrict__ bias,
        void* __restrict__ Cout){
  __shared__ __align__(1024) char lds[98304];
  const int tid = threadIdx.x, wid = tid>>6, lane = tid&63, g = lane>>4, c16 = lane&15;
  const int wm = wid>>2, wn = wid&3;
  const int orig = blockIdx.x;
  const int wg = (orig & 7)*32 + (orig >> 3);   // bijective XCD swizzle (grid 256)
  const int bm = wg & 31, bn = wg >> 5;
  const int rowA0 = bm*128, rowB0 = bn*256;
  const char* Ab8 = (const char*)A + (size_t)rowA0*4096;
  const char* Bb8 = (const char*)Bw + (size_t)rowB0*4096;

  f32x4 acc[4][4] = {};

  auto stage = [&](int t, int b){
    char* ad = lds + b*49152;
    char* bd = lds + b*49152 + 16384;
    #pragma unroll
    for (int i=0;i<2;i++){
      int off = i*8192 + tid*16;
      int r = off >> 7;
      int cs = (off & 127) ^ ((r&7)<<4);
      gload16(Ab8 + (size_t)r*4096 + t*128 + cs, ad + i*8192 + wid*1024);
    }
    #pragma unroll
    for (int i=0;i<4;i++){
      int off = i*8192 + tid*16;
      int r = off >> 7;
      int cs = (off & 127) ^ ((r&7)<<4);
      gload16(Bb8 + (size_t)r*4096 + t*128 + cs, bd + i*8192 + wid*1024);
    }
  };

  auto compute = [&](int b){
    const char* Abuf = lds + b*49152;
    const char* Bbuf = lds + b*49152 + 16384;
    bf16x8 bfr[4][2];
    #pragma unroll
    for (int ni=0;ni<4;ni++){
      int r = wn*64 + ni*16 + c16;
      int sw = (r&7)<<4;
      #pragma unroll
      for (int kk=0;kk<2;kk++)
        bfr[ni][kk] = *(const bf16x8*)(Bbuf + r*128 + ((kk*64 + g*16) ^ sw));
    }
    #pragma unroll
    for (int mi=0;mi<4;mi++){
      int r = wm*64 + mi*16 + c16;
      int sw = (r&7)<<4;
      bf16x8 af0 = *(const bf16x8*)(Abuf + r*128 + ((g*16) ^ sw));
      bf16x8 af1 = *(const bf16x8*)(Abuf + r*128 + ((64 + g*16) ^ sw));
      __builtin_amdgcn_s_setprio(1);
      #pragma unroll
      for (int ni=0;ni<4;ni++){
        acc[mi][ni] = __builtin_amdgcn_mfma_f32_16x16x32_bf16(af0, bfr[ni][0], acc[mi][ni],0,0,0);
        acc[mi][ni] = __builtin_amdgcn_mfma_f32_16x16x32_bf16(af1, bfr[ni][1], acc[mi][ni],0,0,0);
      }
      __builtin_amdgcn_s_setprio(0);
    }
  };

  stage(0,0);
  stage(1,1);
  asm volatile("s_waitcnt vmcnt(6)" ::: "memory");
  asm volatile("s_barrier" ::: "memory");

  #pragma unroll 1
  for (int tt = 0; tt < 32; tt += 2){
    compute(0);
    asm volatile("s_barrier" ::: "memory");
    if (tt + 2 < 32){ stage(tt+2, 0); asm volatile("s_waitcnt vmcnt(6)" ::: "memory"); }
    else            {                 asm volatile("s_waitcnt vmcnt(0)" ::: "memory"); }
    asm volatile("s_barrier" ::: "memory");
    compute(1);
    if (tt + 2 < 32){
      asm volatile("s_barrier" ::: "memory");
      if (tt + 3 < 32){ stage(tt+3, 1); asm volatile("s_waitcnt vmcnt(6)" ::: "memory"); }
      else            {                 asm volatile("s_waitcnt vmcnt(0)" ::: "memory"); }
      asm volatile("s_barrier" ::: "memory");
    }
  }

  #pragma unroll
  for (int mi=0;mi<4;mi++){
    #pragma unroll
    for (int ni=0;ni<4;ni++){
      int f = rowB0 + wn*64 + ni*16 + c16;
      float bv = bias[f];
      #pragma unroll
      for (int j=0;j<4;j++){
        int m = rowA0 + wm*64 + mi*16 + g*4 + j;
        float v = acc[mi][ni][j] + bv;
        if constexpr (MODE == 0) {
          ((__hip_bfloat16*)Cout)[(size_t)m*EE + f] = f2bf(v);
        } else if constexpr (MODE == 1) {
          int b = m >> 11, s = m & (SS-1);
          ((__hip_bfloat16*)Cout)[((size_t)(b*EE + f))*SS + s] = f2bf(v);
        } else {
          ((float*)Cout)[(size_t)m*EE + f] = v;
        }
      }
    }
  }
}

// ---------------- flash attention (causal), swapped-QK^T 32x32x16, 4 waves x 32q ----------------
// R4 structure + WAVE-PHASE SKEW: waves 2,3 defer PV by one iteration so that
// at any instant ~half the block's waves are in an MFMA phase while the other
// half are in VALU/LDS (R11 diagnosis: per-iter cost == serial sum of pipes).
// V triple-buffered (80KB LDS total, 2 blocks/CU). Deferred PV(it-1) executes
// BEFORE softmax(it)'s rescale -> online-softmax algebra exact.
__global__ __launch_bounds__(256, 2) void attn_kernel(const __hip_bfloat16* __restrict__ qg,
    const __hip_bfloat16* __restrict__ kg, const __hip_bfloat16* __restrict__ vtg,
    __hip_bfloat16* __restrict__ og){
  __shared__ short Ks[2][64*128];    // 16KB x2
  __shared__ short Vs3[3][128*64];   // 16KB x3
  const int tid=threadIdx.x, wid=tid>>6, lane=tid&63;
  const int c32 = lane & 31, hi = lane >> 5;
  const bool skew = (wid >= 2);
  const int id = blockIdx.x;
  const int u = id & 255;
  const int bh = u & 31, pr = u >> 5;
  const int qtile = (id < 256) ? (15 - pr) : pr;
  const int b = bh >> 4, h = bh & 15;
  const int q0 = qtile*128, qw = q0 + wid*32;
  const int qglob = qw + c32;
  const int niter = 2*qtile + 2;

  const char* kb8 = (const char*)(kg + ((size_t)b*SS)*EE + h*DD);
  const char* vb8 = (const char*)(vtg + (size_t)bh*DD*SS);

  // Q row for this lane: 8 x bf16x8 covering d=0..127
  const char* qrow = (const char*)(qg + ((size_t)(b*SS + qglob))*EE + h*DD);
  bf16x8 qf[8];
  #pragma unroll
  for (int s=0;s<8;s++) qf[s] = *(const bf16x8*)(qrow + s*32 + hi*16);

  f32x16 pacc[4] = {};
  float mrun = -INFINITY, lrun = 0.f;
  bf16x8 pf[4];   // persists across iterations for skewed waves

  auto stageK = [&](int kv, short* dst){
    #pragma unroll
    for (int i=0;i<4;i++){
      int base = i*4096 + wid*1024;
      int lb = base + lane*16;
      int r = lb >> 8, cb = lb & 255;
      gload16(kb8 + (size_t)(kv + r)*4096 + (cb ^ ((r&7)<<4)), (char*)dst + base);
    }
  };
  auto stageV = [&](int kv, short* dst){
    #pragma unroll
    for (int i=0;i<4;i++){
      int base = i*4096 + wid*1024;
      int lb = base + lane*16;
      int d = lb >> 7, cb = lb & 127;
      gload16(vb8 + (size_t)d*4096 + (size_t)kv*2 + (cb ^ ((d&7)<<4)), (char*)dst + base);
    }
  };
  auto pvadd = [&](const short* vbuf){
    const char* Vb = (const char*)vbuf;
    const int vsw = (c32 & 7) << 4;
    __builtin_amdgcn_s_setprio(1);
    #pragma unroll
    for (int ds=0; ds<4; ds++){
      const char* vr = Vb + (ds*32 + c32)*128;
      #pragma unroll
      for (int ks=0; ks<4; ks++){
        bf16x8 vf = *(const bf16x8*)(vr + ((ks*32 + hi*16) ^ vsw));
        pacc[ds] = __builtin_amdgcn_mfma_f32_32x32x16_bf16(vf, pf[ks], pacc[ds], 0,0,0);
      }
    }
    __builtin_amdgcn_s_setprio(0);
  };

  // V buffer roles: va = V(it-1), vb = V(it), vc = staging target V(it+1)
  short* va = Vs3[0]; short* vbuf = Vs3[1]; short* vc = Vs3[2];
  short* kc = Ks[0];  short* kn = Ks[1];

  stageK(0, kc); stageV(0, vbuf);
  __syncthreads();

  #pragma unroll 1
  for (int it = 0; it < niter; ++it){
    const int kv0 = it*64;
    if (it + 1 < niter){ stageK(kv0+64, kn); stageV(kv0+64, vc); }

    // ---- skewed waves: deferred PV(it-1) from va (staged 2 slots ago, safe) ----
    if (skew && it > 0) pvadd(va);

    // ---- QK^T: S^T[64kv x 32q], two 32-kv subtiles ----
    f32x16 st0 = {}, st1 = {};
    {
      const char* Kb = (const char*)kc;
      const int sw = (c32 & 7) << 4;
      __builtin_amdgcn_s_setprio(1);
      #pragma unroll
      for (int s=0;s<8;s++){
        bf16x8 kf0 = *(const bf16x8*)(Kb + c32*256        + ((s*32 + hi*16) ^ sw));
        bf16x8 kf1 = *(const bf16x8*)(Kb + (32+c32)*256   + ((s*32 + hi*16) ^ sw));
        st0 = __builtin_amdgcn_mfma_f32_32x32x16_bf16(kf0, qf[s], st0, 0,0,0);
        st1 = __builtin_amdgcn_mfma_f32_32x32x16_bf16(kf1, qf[s], st1, 0,0,0);
      }
      __builtin_amdgcn_s_setprio(0);
    }

    // ---- mask + in-register online softmax (q = lane column; S pre-scaled) ----
    float p[32];
    float vmax = -INFINITY;
    const bool domask = (kv0 + 63 > qw);
    #pragma unroll
    for (int r=0;r<16;r++){
      float v0 = st0[r], v1 = st1[r];
      if (domask){
        int kvo = (r&3) + 8*(r>>2) + 4*hi;
        if (kv0 + kvo > qglob)      v0 = -INFINITY;
        if (kv0 + 32 + kvo > qglob) v1 = -INFINITY;
      }
      p[r] = v0; p[16+r] = v1;
      vmax = fmaxf(vmax, fmaxf(v0, v1));
    }
    vmax = fmaxf(vmax, __shfl_xor(vmax, 32));

    const bool anynew = !__all(vmax <= mrun);
    float mnew = mrun;
    if (anynew){
      mnew = fmaxf(mrun, vmax);
      const float rs = exp2f(mrun - mnew);
      mrun = mnew;
      lrun *= rs;
      #pragma unroll
      for (int ds=0; ds<4; ds++)
        #pragma unroll
        for (int r=0;r<16;r++) pacc[ds][r] *= rs;
    }

    float s0=0.f, s1=0.f, s2=0.f, s3=0.f;
    #pragma unroll
    for (int i=0;i<8;i++){
      p[i]    = exp2f(p[i]    - mnew); s0 += p[i];
      p[8+i]  = exp2f(p[8+i]  - mnew); s1 += p[8+i];
      p[16+i] = exp2f(p[16+i] - mnew); s2 += p[16+i];
      p[24+i] = exp2f(p[24+i] - mnew); s3 += p[24+i];
    }
    float ps = (s0 + s1) + (s2 + s3);
    ps += __shfl_xor(ps, 32);
    lrun += ps;

    // ---- pack P to bf16 words: w[T][m][u] holds kv = 32T + 8m + 4hi + 2u ----
    unsigned w[2][4][2];
    #pragma unroll
    for (int T=0;T<2;T++)
      #pragma unroll
      for (int m=0;m<4;m++)
        #pragma unroll
        for (int uu=0;uu<2;uu++)
          w[T][m][uu] = pk2(p[T*16 + 4*m + 2*uu], p[T*16 + 4*m + 2*uu + 1]);

    // ---- build PV B-fragments: pf[ks] covers kv = 16ks + 8hi + 0..7 ----
    #pragma unroll
    for (int ks=0; ks<4; ks++){
      int T = ks>>1, lo2 = (ks&1)*2;
      unsigned o0 = hi ? w[T][lo2+1][0] : w[T][lo2+0][0];
      unsigned o1 = hi ? w[T][lo2+1][1] : w[T][lo2+0][1];
      unsigned x0 = hi ? w[T][lo2+0][0] : w[T][lo2+1][0];
      unsigned x1 = hi ? w[T][lo2+0][1] : w[T][lo2+1][1];
      unsigned r0 = (unsigned)__shfl_xor((int)x0, 32);
      unsigned r1 = (unsigned)__shfl_xor((int)x1, 32);
      union { u32x4 u4; bf16x8 h8; } cvt;
      cvt.u4[0] = hi ? r0 : o0;
      cvt.u4[1] = hi ? r1 : o1;
      cvt.u4[2] = hi ? o0 : r0;
      cvt.u4[3] = hi ? o1 : r1;
      pf[ks] = cvt.h8;
    }

    // ---- non-skew waves: PV(it) now; skew waves carry pf to next slot ----
    if (!skew) pvadd(vbuf);

    __syncthreads();
    // rotate buffers: va <- V(it), vb <- V(it+1), vc <- old va (next target)
    short* t = va; va = vbuf; vbuf = vc; vc = t;
    short* tk = kc; kc = kn; kn = tk;
  }

  // skewed waves: final deferred PV(niter-1); va == V(niter-1) after rotation
  if (skew) pvadd(va);

  // ---- epilogue: O[q][d] = pacc^T / lrun ----
  const float invl = 1.0f / lrun;
  char* orow = (char*)(og + ((size_t)(b*SS + qglob))*EE + h*DD);
  #pragma unroll
  for (int ds=0; ds<4; ds++){
    #pragma unroll
    for (int m=0;m<4;m++){
      int d0 = ds*32 + 8*m + 4*hi;
      short4 s4;
      s4.x = f2bs(pacc[ds][4*m+0]*invl);
      s4.y = f2bs(pacc[ds][4*m+1]*invl);
      s4.z = f2bs(pacc[ds][4*m+2]*invl);
      s4.w = f2bs(pacc[ds][4*m+3]*invl);
      *(short4*)(orow + d0*2) = s4;
    }
  }
}

extern "C" void kernel_launch(void* const* d_in, const int* in_sizes, int n_in,
                              void* d_out, int out_size, void* d_ws, size_t ws_size,
                              hipStream_t stream){
  const float* x  = (const float*)d_in[0];
  const float* Wq = (const float*)d_in[1];
  const float* bq = (const float*)d_in[2];
  const float* Wk = (const float*)d_in[3];
  const float* bk = (const float*)d_in[4];
  const float* Wv = (const float*)d_in[5];
  const float* bv = (const float*)d_in[6];
  const float* Wp = (const float*)d_in[7];
  const float* bp = (const float*)d_in[8];
  float* out = (float*)d_out;

  char* ws = (char*)d_ws;
  size_t off = 0;
  auto alloc = [&](size_t bytes){ void* p = ws + off; off += (bytes + 255) & ~(size_t)255; return p; };
  const size_t nx = (size_t)MM*EE;
  const size_t nw = (size_t)EE*EE;
  __hip_bfloat16* xb  = (__hip_bfloat16*)alloc(nx*2);
  __hip_bfloat16* wqb = (__hip_bfloat16*)alloc(nw*2);
  __hip_bfloat16* wkb = (__hip_bfloat16*)alloc(nw*2);
  __hip_bfloat16* wvb = (__hip_bfloat16*)alloc(nw*2);
  __hip_bfloat16* wpb = (__hip_bfloat16*)alloc(nw*2);
  __hip_bfloat16* qb  = (__hip_bfloat16*)alloc(nx*2);
  __hip_bfloat16* kb  = (__hip_bfloat16*)alloc(nx*2);
  __hip_bfloat16* vtb = (__hip_bfloat16*)alloc(nx*2);
  __hip_bfloat16* ob  = (__hip_bfloat16*)alloc(nx*2);
  float* cost = (float*)alloc((size_t)SS*64*4);
  float* sint = (float*)alloc((size_t)SS*64*4);

  cvt_kernel<<<(int)(nx/4/256), 256, 0, stream>>>(x, xb, (int)(nx/4));
  P4 p4{Wq, Wk, Wv, Wp, wqb, wkb, wvb, wpb};
  cvt4_kernel<<<dim3((int)(nw/4/256), 4), 256, 0, stream>>>(p4, (int)(nw/4));
  rope_tables_kernel<<<SS*64/256, 256, 0, stream>>>(cost, sint);

  gemm256<0><<<256, 512, 0, stream>>>(xb, wqb, bq, qb);
  gemm256<0><<<256, 512, 0, stream>>>(xb, wkb, bk, kb);
  gemm256<1><<<256, 512, 0, stream>>>(xb, wvb, bv, vtb);

  rope_kernel<<<(BB*SS*HH*64)/256, 256, 0, stream>>>(qb, kb, cost, sint);

  attn_kernel<<<dim3(512), 256, 0, stream>>>(qb, kb, vtb, ob);

  gemm256<2><<<256, 512, 0, stream>>>(ob, wpb, bp, out);
}